// Round 10
// baseline (1610.407 us; speedup 1.0000x reference)
//
#include <hip/hip_runtime.h>

#define BB 256
#define TT 1024
#define II 3
#define HH 128
#define OO 3
#define NT 64    // ONE wave per block; one batch element per block; no barriers

#if __has_builtin(__builtin_amdgcn_exp2f)
#define EXP2F __builtin_amdgcn_exp2f
#else
#define EXP2F exp2f
#endif
#if __has_builtin(__builtin_amdgcn_rcpf)
#define RCPF __builtin_amdgcn_rcpf
#else
#define RCPF(x) (1.0f / (x))
#endif

typedef __attribute__((ext_vector_type(2))) float f2;

// tanh(x) = 1 - 2/(e^{2x}+1)
__device__ __forceinline__ float fast_tanh(float x) {
    float e = EXP2F(x * 2.885390081777927f);
    return 1.0f - 2.0f * RCPF(e + 1.0f);
}

// packed fp32 FMA (2 MACs/inst); compiler won't form it from scalar fmaf
__device__ __forceinline__ f2 pk_fma(f2 a, f2 b, f2 c) {
    f2 d;
    asm("v_pk_fma_f32 %0, %1, %2, %3" : "=v"(d) : "v"(a), "v"(b), "v"(c));
    return d;
}

// Compiler-level memory-order pin: prevents hoisting subsequent LDS reads
// above the preceding LDS write. (HW: DS ops from one wave execute in
// program order, so emission order == execution order == correctness.)
__device__ __forceinline__ void lds_order() { asm volatile("" ::: "memory"); }

template <int CTRL>
__device__ __forceinline__ float dpp_add(float p) {
    return p + __uint_as_float(__builtin_amdgcn_update_dpp(
        0, (int)__float_as_uint(p), CTRL, 0xF, 0xF, true));
}
#define DPP_XOR1 0xB1   // quad_perm [1,0,3,2]
#define DPP_XOR2 0x4E   // quad_perm [2,3,0,1]
#define DPP_HMIR 0x141  // row_half_mirror: lane^7 within 8
#define DPP_MIRR 0x140  // row_mirror: lane^15 within 16

// ===========================================================================
// SINGLE-WAVE RECURRENCE (round 10 = round 9 with the half-K bug fixed).
// One 64-lane wave per batch element; lane l owns outputs h[2l], h[2l+1]
// with the FULL K=128 in-lane (W_hh rows 2l,2l+1 in 256 VGPRs, f2-packed).
// Per step, with NO barrier anywhere:
//   32x ds_read_b128 (uniform-address broadcast, conflict-free, loaded in
//   4 groups of 8 to bound live registers) -> whole h
//   128x v_pk_fma_f32 (4 indep chains per output) -> two full-K dots
//   tanh x2 -> ds_write_b64 h update (same-wave DS order self-synchronizes)
//   hid[t] stored straight from registers (coalesced 512B/wave)
//   out-projection partials (6 FMA + 12 DPP) -> psum[t&1]; finished for
//   t-1 from psum[(t-1)&1] next iteration (same-wave in-order, race-free).
// ===========================================================================
__global__ __launch_bounds__(NT, 1) void rnn_kernel(
    const float* __restrict__ x,     // [B,T,I]
    const float* __restrict__ Wih,   // [H,I]
    const float* __restrict__ Whh,   // [H,H]
    const float* __restrict__ bih,   // [H]
    const float* __restrict__ bhh,   // [H]
    const float* __restrict__ h0,    // [1,H]
    const float* __restrict__ Wout,  // [O,H]
    const float* __restrict__ bout,  // [O]
    float* __restrict__ out,         // [B,T,O]
    float* __restrict__ hid)         // [B,T,H]
{
    __shared__ __align__(16) float4 xs[TT];      // 16 KB staged inputs
    __shared__ __align__(16) float hbuf[HH];     // single-buffer hidden state
    __shared__ __align__(16) float psum[2][12];  // projection partials (dbuf)

    const int lane = threadIdx.x;   // 0..63
    const int b = blockIdx.x;

    // ---- stage x: lane covers flat [lane*48, lane*48+48) = 16 timesteps ----
    {
        const float* xb = x + (size_t)b * TT * II;
        const float4* xb4 = (const float4*)xb + lane * 12;
        float v[48];
#pragma unroll
        for (int j = 0; j < 12; ++j) {
            float4 q = xb4[j];
            v[4 * j + 0] = q.x; v[4 * j + 1] = q.y;
            v[4 * j + 2] = q.z; v[4 * j + 3] = q.w;
        }
#pragma unroll
        for (int tt = 0; tt < 16; ++tt)
            xs[lane * 16 + tt] =
                float4{v[3 * tt], v[3 * tt + 1], v[3 * tt + 2], 0.f};
    }
    // ---- init h(0) ----
    ((float2*)hbuf)[lane] = ((const float2*)h0)[lane];
    lds_order();

    // ---- W_hh rows 2l, 2l+1 into 256 VGPRs (f2-packed) ----
    f2 w0[64], w1[64];
    {
        const float4* r0 = (const float4*)(Whh + (size_t)(2 * lane) * HH);
        const float4* r1 = (const float4*)(Whh + (size_t)(2 * lane + 1) * HH);
#pragma unroll
        for (int c = 0; c < 32; ++c) {
            float4 a = r0[c];
            w0[2 * c]     = f2{a.x, a.y};
            w0[2 * c + 1] = f2{a.z, a.w};
            float4 q = r1[c];
            w1[2 * c]     = f2{q.x, q.y};
            w1[2 * c + 1] = f2{q.z, q.w};
        }
    }
    // input projection weights + fused bias for the lane's two rows
    const int r0i = 2 * lane, r1i = 2 * lane + 1;
    const float wi00 = Wih[r0i * II + 0], wi01 = Wih[r0i * II + 1], wi02 = Wih[r0i * II + 2];
    const float wi10 = Wih[r1i * II + 0], wi11 = Wih[r1i * II + 1], wi12 = Wih[r1i * II + 2];
    const float bias0 = bih[r0i] + bhh[r0i];
    const float bias1 = bih[r1i] + bhh[r1i];
    // out-projection weights for the lane's two h, plus lane<3 bias
    const float wo00 = Wout[0 * HH + 2 * lane], wo01 = Wout[0 * HH + 2 * lane + 1];
    const float wo10 = Wout[1 * HH + 2 * lane], wo11 = Wout[1 * HH + 2 * lane + 1];
    const float wo20 = Wout[2 * HH + 2 * lane], wo21 = Wout[2 * HH + 2 * lane + 1];
    const float boL = (lane < OO) ? bout[lane] : 0.f;

    float2* hb2 = (float2*)(hid + (size_t)b * TT * HH);
    float* ob = out + (size_t)b * TT * OO;
    const float4* hb4 = (const float4*)hbuf;
    const int o = lane & 15;

    for (int t = 0; t < TT; ++t) {
        const int par = t & 1;
        // ---- finish out[t-1] from previous step's psum (in-order, no sync) --
        if (t > 0 && lane < OO) {
            const float* pp = psum[par ^ 1];
            float4 g4 = *(const float4*)(pp + lane * 4);
            ob[(size_t)(t - 1) * OO + lane] =
                ((g4.x + g4.y) + (g4.z + g4.w)) + boL;
        }
        float4 xv = xs[t];
        // ---- FULL K=128: 32 broadcast b128 in 4 groups of 8; 128 pk_fma ----
        f2 a0[4] = {f2{0.f, 0.f}, f2{0.f, 0.f}, f2{0.f, 0.f}, f2{0.f, 0.f}};
        f2 a1[4] = {f2{0.f, 0.f}, f2{0.f, 0.f}, f2{0.f, 0.f}, f2{0.f, 0.f}};
#pragma unroll
        for (int gq = 0; gq < 4; ++gq) {
            float4 hcg[8];
#pragma unroll
            for (int j = 0; j < 8; ++j) hcg[j] = hb4[gq * 8 + j];
#pragma unroll
            for (int j = 0; j < 8; ++j) {
                const int c = gq * 8 + j;
                f2 hh0 = f2{hcg[j].x, hcg[j].y};
                f2 hh1 = f2{hcg[j].z, hcg[j].w};
                a0[c & 3] = pk_fma(w0[2 * c],     hh0, a0[c & 3]);
                a0[c & 3] = pk_fma(w0[2 * c + 1], hh1, a0[c & 3]);
                a1[c & 3] = pk_fma(w1[2 * c],     hh0, a1[c & 3]);
                a1[c & 3] = pk_fma(w1[2 * c + 1], hh1, a1[c & 3]);
            }
        }
        f2 s0v = (a0[0] + a0[1]) + (a0[2] + a0[3]);
        f2 s1v = (a1[0] + a1[1]) + (a1[2] + a1[3]);
        float xp0 = fmaf(xv.z, wi02, fmaf(xv.y, wi01, fmaf(xv.x, wi00, bias0)));
        float xp1 = fmaf(xv.z, wi12, fmaf(xv.y, wi11, fmaf(xv.x, wi10, bias1)));
        float val0 = fast_tanh((s0v.x + s0v.y) + xp0);
        float val1 = fast_tanh((s1v.x + s1v.y) + xp1);
        float2 hv = float2{val0, val1};
        ((float2*)hbuf)[lane] = hv;          // LDS h update
        lds_order();                         // keep DS program order vs next reads
        hb2[(size_t)t * 64 + lane] = hv;     // hid[b][t] store, coalesced 512B
        // ---- projection partials for out[t] (rides the latency bubble) ----
        float p0 = fmaf(wo01, val1, wo00 * val0);
        float p1 = fmaf(wo11, val1, wo10 * val0);
        float p2 = fmaf(wo21, val1, wo20 * val0);
        p0 = dpp_add<DPP_XOR1>(p0); p0 = dpp_add<DPP_XOR2>(p0);
        p0 = dpp_add<DPP_HMIR>(p0); p0 = dpp_add<DPP_MIRR>(p0);
        p1 = dpp_add<DPP_XOR1>(p1); p1 = dpp_add<DPP_XOR2>(p1);
        p1 = dpp_add<DPP_HMIR>(p1); p1 = dpp_add<DPP_MIRR>(p1);
        p2 = dpp_add<DPP_XOR1>(p2); p2 = dpp_add<DPP_XOR2>(p2);
        p2 = dpp_add<DPP_HMIR>(p2); p2 = dpp_add<DPP_MIRR>(p2);
        if (o < OO) {   // 12 lanes: group g=lane>>4, output o
            float pv = (o == 0) ? p0 : (o == 1) ? p1 : p2;
            psum[par][o * 4 + (lane >> 4)] = pv;
        }
        lds_order();
    }
    // ---- tail: out[TT-1] ----
    if (lane < OO) {
        const float* pp = psum[(TT - 1) & 1];
        float4 g4 = *(const float4*)(pp + lane * 4);
        ob[(size_t)(TT - 1) * OO + lane] =
            ((g4.x + g4.y) + (g4.z + g4.w)) + boL;
    }
}

extern "C" void kernel_launch(void* const* d_in, const int* in_sizes, int n_in,
                              void* d_out, int out_size, void* d_ws, size_t ws_size,
                              hipStream_t stream) {
    const float* x    = (const float*)d_in[0];  // [256,1024,3]
    const float* Wih  = (const float*)d_in[1];  // [128,3]
    const float* Whh  = (const float*)d_in[2];  // [128,128]
    const float* bih  = (const float*)d_in[3];  // [128]
    const float* bhh  = (const float*)d_in[4];  // [128]
    const float* h0   = (const float*)d_in[5];  // [1,128]
    const float* Wout = (const float*)d_in[6];  // [3,128]
    const float* bout = (const float*)d_in[7];  // [3]

    float* out = (float*)d_out;                 // [B,T,O] first
    float* hid = out + (size_t)BB * TT * OO;    // then [B,T,H]

    rnn_kernel<<<BB, NT, 0, stream>>>(x, Wih, Whh, bih, bhh, h0, Wout, bout, out, hid);
}